// Round 1
// baseline (1438.569 us; speedup 1.0000x reference)
//
#include <hip/hip_runtime.h>

// ============================================================================
// GCN link-prediction pipeline, fp32.
//   deg/dinv -> CSR(dst) build -> 4x (GEMM 128x128 + pull-aggregate)
//   -> U/V = h @ Wl1 halves -> per-pair logits + log_softmax
// ============================================================================

// ---------------- CSR build ----------------
__global__ void k_count(const int* __restrict__ dst, int* __restrict__ cnt, int E) {
  int i = blockIdx.x * blockDim.x + threadIdx.x;
  if (i < E) atomicAdd(&cnt[dst[i]], 1);
}

__global__ void k_dinv(const int* __restrict__ cnt, float* __restrict__ dinv, int n) {
  int i = blockIdx.x * blockDim.x + threadIdx.x;
  if (i < n) dinv[i] = rsqrtf((float)(cnt[i] + 1));  // +1 self-loop; deg>=1 always
}

#define SCHUNK 1024
__global__ void k_chunk_sum(const int* __restrict__ cnt, int* __restrict__ csum, int n) {
  __shared__ int sd[256];
  int c = blockIdx.x, t = threadIdx.x;
  int base = c * SCHUNK;
  int s = 0;
#pragma unroll
  for (int j = 0; j < 4; ++j) {
    int i = base + j * 256 + t;
    if (i < n) s += cnt[i];
  }
  sd[t] = s;
  __syncthreads();
  for (int off = 128; off > 0; off >>= 1) {
    if (t < off) sd[t] += sd[t + off];
    __syncthreads();
  }
  if (t == 0) csum[c] = sd[0];
}

__global__ void k_scan_partials(int* __restrict__ csum, int nc, int* __restrict__ offs, int n) {
  if (threadIdx.x == 0 && blockIdx.x == 0) {
    int run = 0;
    for (int i = 0; i < nc; ++i) { int v = csum[i]; csum[i] = run; run += v; }
    offs[n] = run;  // total = E
  }
}

__global__ void k_chunk_scan(const int* __restrict__ cnt, const int* __restrict__ csum,
                             int* __restrict__ offs, int n) {
  __shared__ int ts[256];
  int c = blockIdx.x, t = threadIdx.x;
  int i0 = c * SCHUNK + t * 4;
  int v0 = 0, v1 = 0, v2 = 0, v3 = 0;
  if (i0 + 0 < n) v0 = cnt[i0 + 0];
  if (i0 + 1 < n) v1 = cnt[i0 + 1];
  if (i0 + 2 < n) v2 = cnt[i0 + 2];
  if (i0 + 3 < n) v3 = cnt[i0 + 3];
  int s = v0 + v1 + v2 + v3;
  ts[t] = s;
  __syncthreads();
  for (int off = 1; off < 256; off <<= 1) {
    int x = (t >= off) ? ts[t - off] : 0;
    __syncthreads();
    ts[t] += x;
    __syncthreads();
  }
  int run = csum[c] + ts[t] - s;  // exclusive prefix for this thread
  if (i0 + 0 < n) { offs[i0 + 0] = run; run += v0; }
  if (i0 + 1 < n) { offs[i0 + 1] = run; run += v1; }
  if (i0 + 2 < n) { offs[i0 + 2] = run; run += v2; }
  if (i0 + 3 < n) { offs[i0 + 3] = run; run += v3; }
}

__global__ void k_fill(const int* __restrict__ src, const int* __restrict__ dst,
                       int* __restrict__ cursor, int* __restrict__ csr_src,
                       float* __restrict__ csr_w, const float* __restrict__ dinv, int E) {
  int i = blockIdx.x * blockDim.x + threadIdx.x;
  if (i >= E) return;
  int s = src[i], d = dst[i];
  int pos = atomicAdd(&cursor[d], 1);
  csr_src[pos] = s;
  csr_w[pos] = dinv[s] * dinv[d];
}

// ---------------- GEMM: O[M][ldo] = A[M][128] @ W[128][128] ----------------
// Block: 256 thr, 64-row tile. W fully in LDS (64KB) + X transposed (34KB).
// Thread tile 8 rows x 4 cols -> 32 fp32 FMA per k-step, 3 ds_read_b128 per k.
__global__ __launch_bounds__(256) void k_gemm(const float* __restrict__ A,
                                              const float* __restrict__ W,
                                              float* __restrict__ O, int M, int ldo) {
  __shared__ float Ws[128 * 128];   // [k][j]
  __shared__ float Xs[128 * 68];    // transposed: Xs[k*68 + r], pad 68 vs banks
  const int tid = threadIdx.x;
  const int row0 = blockIdx.x * 64;
#pragma unroll
  for (int i = 0; i < 16; ++i) {    // stage W: 16384 floats, coalesced float4
    int idx = (tid + i * 256) * 4;
    *(float4*)(Ws + idx) = *(const float4*)(W + idx);
  }
  {
    int tx = tid & 31, tyw = tid >> 5;
#pragma unroll
    for (int it = 0; it < 8; ++it) {
      int r = it * 8 + tyw;
      int row = row0 + r;
      float4 v = make_float4(0.f, 0.f, 0.f, 0.f);
      if (row < M) v = *(const float4*)(A + (size_t)row * 128 + tx * 4);
      int cc = tx * 4;
      Xs[(cc + 0) * 68 + r] = v.x;
      Xs[(cc + 1) * 68 + r] = v.y;
      Xs[(cc + 2) * 68 + r] = v.z;
      Xs[(cc + 3) * 68 + r] = v.w;
    }
  }
  __syncthreads();
  const int tx = tid & 31;  // cols tx*4 .. tx*4+3
  const int ty = tid >> 5;  // rows ty*8 .. ty*8+7
  float acc[8][4];
#pragma unroll
  for (int i = 0; i < 8; ++i)
#pragma unroll
    for (int j = 0; j < 4; ++j) acc[i][j] = 0.f;
#pragma unroll 8
  for (int k = 0; k < 128; ++k) {
    float4 wv = *(const float4*)(Ws + k * 128 + tx * 4);
    float4 xa = *(const float4*)(Xs + k * 68 + ty * 8);
    float4 xb = *(const float4*)(Xs + k * 68 + ty * 8 + 4);
    float xs[8] = {xa.x, xa.y, xa.z, xa.w, xb.x, xb.y, xb.z, xb.w};
    float wj[4] = {wv.x, wv.y, wv.z, wv.w};
#pragma unroll
    for (int i = 0; i < 8; ++i)
#pragma unroll
      for (int j = 0; j < 4; ++j) acc[i][j] = fmaf(xs[i], wj[j], acc[i][j]);
  }
#pragma unroll
  for (int i = 0; i < 8; ++i) {
    int row = row0 + ty * 8 + i;
    if (row < M) {
      float4 o;
      o.x = acc[i][0]; o.y = acc[i][1]; o.z = acc[i][2]; o.w = acc[i][3];
      *(float4*)(O + (size_t)row * ldo + tx * 4) = o;
    }
  }
}

// ---------------- Pull aggregation: H[i] = sum_e w_e*T[src_e] + dinv_i^2*T[i] + b
__global__ __launch_bounds__(256) void k_aggregate(const float* __restrict__ T,
    float* __restrict__ H, const int* __restrict__ offs,
    const int* __restrict__ csr_src, const float* __restrict__ csr_w,
    const float* __restrict__ dinv, const float* __restrict__ bias,
    int n, int relu) {
  int wid = (int)((blockIdx.x * blockDim.x + threadIdx.x) >> 6);  // one wave per node
  int lane = threadIdx.x & 63;
  if (wid >= n) return;
  float di = dinv[wid];
  float w0 = di * di;
  float2 t0 = *(const float2*)(T + (size_t)wid * 128 + lane * 2);
  float ax = t0.x * w0, ay = t0.y * w0;   // self-loop term
  int e0 = offs[wid], e1 = offs[wid + 1];
  for (int eb = e0; eb < e1; eb += 64) {
    int m = e1 - eb; if (m > 64) m = 64;
    int s = 0; float wv = 0.f;
    if (lane < m) { s = csr_src[eb + lane]; wv = csr_w[eb + lane]; }
    for (int j = 0; j < m; ++j) {
      int sj = __shfl(s, j);
      float wj = __shfl(wv, j);
      float2 tv = *(const float2*)(T + (size_t)sj * 128 + lane * 2);  // 512B/edge, L3-hot
      ax = fmaf(tv.x, wj, ax);
      ay = fmaf(tv.y, wj, ay);
    }
  }
  float2 bv = *(const float2*)(bias + lane * 2);
  ax += bv.x; ay += bv.y;
  if (relu) { ax = fmaxf(ax, 0.f); ay = fmaxf(ay, 0.f); }
  float2 r; r.x = ax; r.y = ay;
  *(float2*)(H + (size_t)wid * 128 + lane * 2) = r;
}

// ---------------- Per-pair predictor: z=relu(U[a]+V[b]+bl1); logits=z@Wl2+bl2
__global__ __launch_bounds__(256) void k_pair(const float* __restrict__ UV,
    const int* __restrict__ pt, const int* __restrict__ nt,
    const int* __restrict__ ps, const int* __restrict__ ns,
    const float* __restrict__ bl1, const float* __restrict__ Wl2,
    const float* __restrict__ bl2, float* __restrict__ out,
    int npt, int nnt, int nps, int nns) {
  int wid = (int)((blockIdx.x * blockDim.x + threadIdx.x) >> 6);  // one wave per pair
  int lane = threadIdx.x & 63;
  int total = npt + nnt + nps + nns;
  if (wid >= total) return;
  int a, b, q = wid;
  if (q < npt)               { a = pt[q]; b = pt[npt + q]; }
  else if ((q -= npt) < nnt) { a = nt[q]; b = nt[nnt + q]; }
  else if ((q -= nnt) < nps) { a = ps[q]; b = ps[nps + q]; }
  else { q -= nps;             a = ns[q]; b = ns[nns + q]; }
  float2 u = *(const float2*)(UV + (size_t)a * 256 + lane * 2);
  float2 v = *(const float2*)(UV + (size_t)b * 256 + 128 + lane * 2);
  float2 bb = *(const float2*)(bl1 + lane * 2);
  float z0 = fmaxf(u.x + v.x + bb.x, 0.f);
  float z1 = fmaxf(u.y + v.y + bb.y, 0.f);
  float4 w2 = *(const float4*)(Wl2 + lane * 4);  // rows 2l,2l+1 of [128][2]
  float p0 = fmaf(z0, w2.x, z1 * w2.z);
  float p1 = fmaf(z0, w2.y, z1 * w2.w);
#pragma unroll
  for (int o = 32; o > 0; o >>= 1) {
    p0 += __shfl_down(p0, o);
    p1 += __shfl_down(p1, o);
  }
  if (lane == 0) {
    p0 += bl2[0]; p1 += bl2[1];
    float m = fmaxf(p0, p1);
    float lse = m + logf(expf(p0 - m) + expf(p1 - m));
    float2 r; r.x = p0 - lse; r.y = p1 - lse;
    *(float2*)(out + (size_t)wid * 2) = r;
  }
}

// ============================================================================
extern "C" void kernel_launch(void* const* d_in, const int* in_sizes, int n_in,
                              void* d_out, int out_size, void* d_ws, size_t ws_size,
                              hipStream_t stream) {
  const float* x   = (const float*)d_in[0];
  const float* W0  = (const float*)d_in[1];
  const float* b0  = (const float*)d_in[2];
  const float* W1  = (const float*)d_in[3];
  const float* b1  = (const float*)d_in[4];
  const float* W2  = (const float*)d_in[5];
  const float* b2  = (const float*)d_in[6];
  const float* W3  = (const float*)d_in[7];
  const float* b3  = (const float*)d_in[8];
  const float* Wl1 = (const float*)d_in[9];
  const float* bl1 = (const float*)d_in[10];
  const float* Wl2 = (const float*)d_in[11];
  const float* bl2 = (const float*)d_in[12];
  const int* edge_index = (const int*)d_in[13];
  const int* pt = (const int*)d_in[14];
  const int* nt = (const int*)d_in[15];
  const int* ps = (const int*)d_in[16];
  const int* ns = (const int*)d_in[17];

  const int n   = in_sizes[0] / 128;
  const int E   = in_sizes[13] / 2;
  const int npt = in_sizes[14] / 2;
  const int nnt = in_sizes[15] / 2;
  const int nps = in_sizes[16] / 2;
  const int nns = in_sizes[17] / 2;
  float* out = (float*)d_out;

  // ---- workspace carve (all 256B-aligned regions) ----
  char* ws = (char*)d_ws;
  size_t off = 0;
  auto alloc = [&](size_t bytes) -> void* {
    void* p = ws + off;
    off += (bytes + 255) & ~(size_t)255;
    return p;
  };
  float* dinv    = (float*)alloc((size_t)n * 4);
  int*   cnt     = (int*)  alloc((size_t)n * 4);
  int*   offs    = (int*)  alloc((size_t)(n + 1) * 4);
  int*   cursor  = (int*)  alloc((size_t)n * 4);
  int*   csum    = (int*)  alloc(256 * 4);
  int*   csr_src = (int*)  alloc((size_t)E * 4);
  float* csr_w   = (float*)alloc((size_t)E * 4);
  float* bufA    = (float*)alloc((size_t)n * 128 * 4);
  float* bufB    = (float*)alloc((size_t)n * 128 * 4);
  float* UV      = (float*)alloc((size_t)n * 256 * 4);
  if (off > ws_size) return;  // insufficient scratch -> fail loudly (poisoned out)

  const int* esrc = edge_index;
  const int* edst = edge_index + E;

  // ---- degree + CSR ----
  hipMemsetAsync(cnt, 0, (size_t)n * 4, stream);
  k_count<<<(E + 255) / 256, 256, 0, stream>>>(edst, cnt, E);
  k_dinv<<<(n + 255) / 256, 256, 0, stream>>>(cnt, dinv, n);
  int nc = (n + SCHUNK - 1) / SCHUNK;
  k_chunk_sum<<<nc, 256, 0, stream>>>(cnt, csum, n);
  k_scan_partials<<<1, 64, 0, stream>>>(csum, nc, offs, n);
  k_chunk_scan<<<nc, 256, 0, stream>>>(cnt, csum, offs, n);
  hipMemcpyAsync(cursor, offs, (size_t)n * 4, hipMemcpyDeviceToDevice, stream);
  k_fill<<<(E + 255) / 256, 256, 0, stream>>>(esrc, edst, cursor, csr_src, csr_w, dinv, E);

  const int gblocks = (n + 63) / 64;
  const int ablocks = (n + 3) / 4;  // 4 waves/block, one wave per node

  // ---- 4 GCN layers ----
  k_gemm<<<gblocks, 256, 0, stream>>>(x, W0, bufB, n, 128);
  k_aggregate<<<ablocks, 256, 0, stream>>>(bufB, bufA, offs, csr_src, csr_w, dinv, b0, n, 1);
  k_gemm<<<gblocks, 256, 0, stream>>>(bufA, W1, bufB, n, 128);
  k_aggregate<<<ablocks, 256, 0, stream>>>(bufB, bufA, offs, csr_src, csr_w, dinv, b1, n, 1);
  k_gemm<<<gblocks, 256, 0, stream>>>(bufA, W2, bufB, n, 128);
  k_aggregate<<<ablocks, 256, 0, stream>>>(bufB, bufA, offs, csr_src, csr_w, dinv, b2, n, 1);
  k_gemm<<<gblocks, 256, 0, stream>>>(bufA, W3, bufB, n, 128);
  k_aggregate<<<ablocks, 256, 0, stream>>>(bufB, bufA, offs, csr_src, csr_w, dinv, b3, n, 0);

  // ---- U = h @ Wl1[:128], V = h @ Wl1[128:], interleaved as UV[n][256] ----
  k_gemm<<<gblocks, 256, 0, stream>>>(bufA, Wl1, UV, n, 256);
  k_gemm<<<gblocks, 256, 0, stream>>>(bufA, Wl1 + 128 * 128, UV + 128, n, 256);

  // ---- pairs -> log-softmax logits ----
  const int total = npt + nnt + nps + nns;
  k_pair<<<(total + 3) / 4, 256, 0, stream>>>(UV, pt, nt, ps, ns, bl1, Wl2, bl2, out,
                                              npt, nnt, nps, nns);
}